// Round 14
// baseline (30.561 us; speedup 1.0000x reference)
//
#include <hip/hip_runtime.h>
#include <stdint.h>

// ---------------- problem constants ----------------
#define B_ROWS 16384
#define LATD   128
#define HIDD   1024

typedef __bf16 bf16x8 __attribute__((ext_vector_type(8)));
typedef float  f32x4  __attribute__((ext_vector_type(4)));
typedef float  f32x4v __attribute__((ext_vector_type(4)));
typedef unsigned short ushort8v __attribute__((ext_vector_type(8)));
typedef unsigned int   uint2v   __attribute__((ext_vector_type(2)));

// ---------------- asm helpers: unsinkable weight loads + counted waits ----------------
template<int N> __device__ __forceinline__ void waitv() {
  asm volatile("s_waitcnt vmcnt(%0)" :: "i"(N) : "memory");
  __builtin_amdgcn_sched_barrier(0);   // rule-18: no MFMA may hoist above the wait
}
__device__ __forceinline__ void gl16(bf16x8& r, const unsigned short* p) {
  asm volatile("global_load_dwordx4 %0, %1, off" : "=v"(r) : "v"(p));
}
template<int OFF> __device__ __forceinline__ void gl16o(bf16x8& r, const unsigned short* p) {
  asm volatile("global_load_dwordx4 %0, %1, off offset:%2" : "=v"(r) : "v"(p), "i"(OFF));
}
// barrier that drains LDS ops only — asm weight loads stay in flight
#define LGKM_BARRIER() do {                                        \
    asm volatile("s_waitcnt lgkmcnt(0)" ::: "memory");             \
    __builtin_amdgcn_s_barrier();                                  \
    asm volatile("" ::: "memory");                                 \
  } while (0)

// ---------------- threefry2x32 (matches JAX, partitionable default) ----------------
struct TF2 { unsigned int a, b; };

#define TF_R(x0,x1,r) { x0 += x1; x1 = ((x1 << (r)) | (x1 >> (32 - (r)))); x1 ^= x0; }

__host__ __device__ constexpr TF2 threefry2x32(unsigned k0, unsigned k1, unsigned c0, unsigned c1) {
  unsigned ks2 = k0 ^ k1 ^ 0x1BD11BDAu;
  unsigned x0 = c0 + k0, x1 = c1 + k1;
  TF_R(x0,x1,13) TF_R(x0,x1,15) TF_R(x0,x1,26) TF_R(x0,x1,6)
  x0 += k1;  x1 += ks2 + 1u;
  TF_R(x0,x1,17) TF_R(x0,x1,29) TF_R(x0,x1,16) TF_R(x0,x1,24)
  x0 += ks2; x1 += k0 + 2u;
  TF_R(x0,x1,13) TF_R(x0,x1,15) TF_R(x0,x1,26) TF_R(x0,x1,6)
  x0 += k0;  x1 += k1 + 3u;
  TF_R(x0,x1,17) TF_R(x0,x1,29) TF_R(x0,x1,16) TF_R(x0,x1,24)
  x0 += k1;  x1 += ks2 + 4u;
  TF_R(x0,x1,13) TF_R(x0,x1,15) TF_R(x0,x1,26) TF_R(x0,x1,6)
  x0 += ks2; x1 += k0 + 5u;
  return {x0, x1};
}

constexpr TF2 NK0 = threefry2x32(0u, 1u, 0u, 0u);  // bin heads
constexpr TF2 NK1 = threefry2x32(0u, 1u, 0u, 1u);  // like heads
constexpr TF2 NK2 = threefry2x32(0u, 1u, 0u, 2u);  // mask heads

__device__ __forceinline__ unsigned short f2bf(float f) {
  unsigned u = __float_as_uint(f);
  return (unsigned short)((u + 0x7fffu + ((u >> 16) & 1u)) >> 16);
}

// ---------------- prep v3 (r12, kept) ----------------
__global__ __launch_bounds__(256) void prep_kernel(
    const float* __restrict__ W1,
    const float* __restrict__ Wnum, const float* __restrict__ Wcat,
    const float* __restrict__ Wbin, const float* __restrict__ Wlike,
    const float* __restrict__ Wmask,
    const float* __restrict__ bnum, const float* __restrict__ bcat,
    const float* __restrict__ bbin, const float* __restrict__ blike,
    const float* __restrict__ bmask,
    unsigned short* __restrict__ W1p,
    unsigned short* __restrict__ Wallp,
    float* __restrict__ ball) {
  __shared__ __align__(16) unsigned short lds[16 * 136];
  const int b = blockIdx.x, t = threadIdx.x;

  if (b < 64) {
    const int n0 = b * 16;
    const int nq = t & 15;
    float v[8];
    #pragma unroll
    for (int i = 0; i < 8; ++i) {
      int k = i * 16 + (t >> 4);
      v[i] = W1[(size_t)k * HIDD + n0 + nq];
    }
    #pragma unroll
    for (int i = 0; i < 8; ++i) {
      int k = i * 16 + (t >> 4);
      lds[nq * 136 + k] = f2bf(v[i]);
    }
    __syncthreads();
    const int ks = t >> 6, l = t & 63;
    const int l15 = l & 15, l4 = (l >> 4);
    ushort8v p = *(const ushort8v*)(lds + l15 * 136 + ks * 32 + l4 * 8);
    *(ushort8v*)(W1p + ((size_t)(b * 4 + ks) * 64 + l) * 8) = p;
  } else if (b < 224) {
    const int q  = b - 64;
    const int nt = q >> 3, kb = q & 7;
    const int n0 = nt * 16, k0 = kb * 128;
    const int n = n0 + (t & 15);
    const float* src = nullptr; int stride = 0;
    if (n < 32)       { src = Wnum  + n;         stride = 32;  }
    else if (n < 230) { src = Wcat  + (n - 32);  stride = 198; }
    else if (n < 238) { src = Wbin  + (n - 230); stride = 8;   }
    else if (n < 240) { src = Wlike + (n - 238); stride = 2;   }
    else if (n < 294) { src = Wmask + (n - 240); stride = 54;  }
    float v[8];
    if (src) {
      #pragma unroll
      for (int i = 0; i < 8; ++i) {
        int kk_loc = i * 16 + (t >> 4);
        v[i] = src[(size_t)(k0 + kk_loc) * stride];
      }
    } else {
      #pragma unroll
      for (int i = 0; i < 8; ++i) v[i] = 0.f;
    }
    #pragma unroll
    for (int i = 0; i < 8; ++i) {
      int kk_loc = i * 16 + (t >> 4);
      lds[(t & 15) * 136 + kk_loc] = f2bf(v[i]);
    }
    __syncthreads();
    const int kt_loc = t >> 6, l = t & 63;
    const int l15 = l & 15, l4 = (l >> 4);
    ushort8v p = *(const ushort8v*)(lds + l15 * 136 + kt_loc * 32 + l4 * 8);
    const int g = nt * 32 + kb * 4 + kt_loc;
    *(ushort8v*)(Wallp + ((size_t)g * 64 + l) * 8) = p;
  } else {
    for (int n = t; n < 320; n += 256) {
      float v = 0.f;
      if (n < 32)       v = bnum [n];
      else if (n < 230) v = bcat [n - 32];
      else if (n < 238) v = bbin [n - 230];
      else if (n < 240) v = blike[n - 238];
      else if (n < 294) v = bmask[n - 240];
      ball[n] = v;
    }
  }
}

// ---------------- main kernel: 256 WGs x 512 thr (8 waves), 64 rows/WG ----------------
// BALANCED phase 2 (r14): wave = (wk = w>>2: K-half, wc = w&3: 80-col quarter).
// Every wave: 5 col-frags x 16 k-groups = 320 MFMA, 80 KB weight stream (was 384/256
// imbalanced). 2-step wk reduction through LDS at the end (r2-proven pattern).
__global__ __launch_bounds__(512, 2) void decoder_kernel(
    const float* __restrict__ z, const float* __restrict__ b1,
    const unsigned short* __restrict__ W1p, const unsigned short* __restrict__ Wallp,
    const float* __restrict__ ball, float* __restrict__ out) {
  __shared__ __align__(16) unsigned char smem[148480];
  unsigned short* zs = (unsigned short*)smem;          // [64][136] bf16
  unsigned char* hbase = smem + 17408;                 // 8 x 16 KB h tiles
  float* outs = (float*)smem;                          // overlay after phase 2

  const int tid  = threadIdx.x;
  const int lane = tid & 63;
  const int w    = tid >> 6;        // 0..7
  const int wc   = w & 3;           // col quarter (80 cols = 5 frags)
  const int wk   = w >> 2;          // K half (k-groups wk*16 .. wk*16+15)
  const int l15  = lane & 15;
  const int l4   = lane >> 4;
  const int r0   = blockIdx.x * 64;

  // ---- stage z tile -> LDS bf16 (NT: streamed once) ----
  #pragma unroll
  for (int it = 0; it < 2; ++it) {
    int ch  = tid + it * 512;
    int row = ch >> 4;
    int k0  = (ch & 15) * 8;
    const float* src = z + (size_t)(r0 + row) * LATD + k0;
    f32x4v f0 = __builtin_nontemporal_load((const f32x4v*)src);
    f32x4v f1 = __builtin_nontemporal_load((const f32x4v*)(src + 4));
    ushort8v p;
    p[0] = f2bf(f0[0]); p[1] = f2bf(f0[1]); p[2] = f2bf(f0[2]); p[3] = f2bf(f0[3]);
    p[4] = f2bf(f1[0]); p[5] = f2bf(f1[1]); p[6] = f2bf(f1[2]); p[7] = f2bf(f1[3]);
    *(ushort8v*)(zs + row * 136 + k0) = p;
  }
  __syncthreads();   // full drain OK: no asm loads issued yet

  const int cb  = wc * 80;          // output col base
  const int nt0 = wc * 5;           // col-frag base
  const int kt0 = wk * 16;          // k-group base for phase 2

  unsigned char* mytile = hbase + w * 16384;

  // ---- plain loads before the asm stream ----
  f32x4 hb1[8];
  #pragma unroll
  for (int ct = 0; ct < 8; ++ct)
    hb1[ct] = *(const f32x4*)(b1 + w * 128 + ct * 16 + l4 * 4);

  bf16x8 za[4][4];
  #pragma unroll
  for (int rt = 0; rt < 4; ++rt)
    #pragma unroll
    for (int ks = 0; ks < 4; ++ks)
      za[rt][ks] = *(const bf16x8*)(zs + (rt * 16 + l15) * 136 + ks * 32 + l4 * 8);

  bf16x8 wq1[2][4];
  const unsigned short* w1b = W1p + (size_t)w * 16384 + lane * 8;
  #pragma unroll
  for (int ct = 0; ct < 2; ++ct) {
    const unsigned short* p = w1b + ct * 2048;
    gl16o<0>(wq1[ct][0], p); gl16o<1024>(wq1[ct][1], p);
    gl16o<2048>(wq1[ct][2], p); gl16o<3072>(wq1[ct][3], p);
  }

  bf16x8 wq2[4][5];                 // ring 4 x 5 col-frags
  const unsigned short* w2b = Wallp + lane * 8;

  // ---- phase 1: wave w computes h chunk w ----
  #pragma unroll
  for (int ct = 0; ct < 8; ++ct) {
    if (ct < 7) waitv<4>();
    else        waitv<20>();        // wq1 g7 arrived; 20 wq2 loads in flight
    f32x4 a[4] = {};
    #pragma unroll
    for (int ks = 0; ks < 4; ++ks)
      #pragma unroll
      for (int rt = 0; rt < 4; ++rt)
        a[rt] = __builtin_amdgcn_mfma_f32_16x16x32_bf16(wq1[ct & 1][ks], za[rt][ks], a[rt], 0, 0, 0);
    #pragma unroll
    for (int rt = 0; rt < 4; ++rt) {
      float v0 = fmaxf(a[rt][0] + hb1[ct][0], 0.f);
      float v1 = fmaxf(a[rt][1] + hb1[ct][1], 0.f);
      float v2 = fmaxf(a[rt][2] + hb1[ct][2], 0.f);
      float v3 = fmaxf(a[rt][3] + hb1[ct][3], 0.f);
      uint2v u;
      u[0] = (unsigned)f2bf(v0) | ((unsigned)f2bf(v1) << 16);
      u[1] = (unsigned)f2bf(v2) | ((unsigned)f2bf(v3) << 16);
      const int byte = ((ct >> 1) * 4 + rt) * 1024
                     + ((ct & 1) * 2 + (l4 >> 1)) * 256
                     + l15 * 16 + (l4 & 1) * 8;
      *(uint2v*)(mytile + byte) = u;
    }
    if (ct < 6) {
      const unsigned short* p = w1b + (ct + 2) * 2048;
      gl16o<0>(wq1[ct & 1][0], p); gl16o<1024>(wq1[ct & 1][1], p);
      gl16o<2048>(wq1[ct & 1][2], p); gl16o<3072>(wq1[ct & 1][3], p);
    } else if (ct == 6) {           // pre-issue phase-2 ring groups 0..3 (20 loads)
      #pragma unroll
      for (int g = 0; g < 4; ++g)
        #pragma unroll
        for (int cc = 0; cc < 5; ++cc)
          gl16(wq2[g][cc], w2b + (size_t)((nt0 + cc) * 32 + kt0 + g) * 512);
    }
  }

  LGKM_BARRIER();    // h visible to all waves; weight prefetches stay in flight

  // ---- phase 2: 16 k-groups (kt = kt0 + g), 5 col-frags, no barriers ----
  f32x4 acc[4][5];
  #pragma unroll
  for (int rt = 0; rt < 4; ++rt)
    #pragma unroll
    for (int ct = 0; ct < 5; ++ct)
      acc[rt][ct] = (f32x4){0.f, 0.f, 0.f, 0.f};

  #pragma unroll
  for (int g = 0; g < 16; ++g) {
    const int rem = 15 - g;          // compile-time after unroll
    if (rem >= 3)      waitv<15>();  // group g landed; 3 groups in flight
    else if (rem == 2) waitv<10>();
    else if (rem == 1) waitv<5>();
    else               waitv<0>();
    const int kt = kt0 + g;
    const unsigned char* hc = hbase + (kt >> 2) * 16384 + (kt & 3) * 4096 + lane * 16;
    #pragma unroll
    for (int rt = 0; rt < 4; ++rt) {
      bf16x8 ha = *(const bf16x8*)(hc + rt * 1024);
      #pragma unroll
      for (int ct = 0; ct < 5; ++ct)
        acc[rt][ct] = __builtin_amdgcn_mfma_f32_16x16x32_bf16(ha, wq2[g & 3][ct], acc[rt][ct], 0, 0, 0);
    }
    if (g + 4 < 16) {
      #pragma unroll
      for (int cc = 0; cc < 5; ++cc)
        gl16(wq2[g & 3][cc], w2b + (size_t)((nt0 + cc) * 32 + kt0 + g + 4) * 512);
    }
  }

  __syncthreads();   // all h reads done everywhere; LDS becomes outs

  // ---- 2-step wk reduction into outs[64][321] (+fused bias) ----
  if (wk == 0) {
    #pragma unroll
    for (int ct = 0; ct < 5; ++ct) {
      float b2 = ball[cb + ct * 16 + l15];
      #pragma unroll
      for (int rt = 0; rt < 4; ++rt)
        #pragma unroll
        for (int j = 0; j < 4; ++j)
          outs[(rt * 16 + l4 * 4 + j) * 321 + cb + ct * 16 + l15] = acc[rt][ct][j] + b2;
    }
  }
  __syncthreads();
  if (wk == 1) {
    #pragma unroll
    for (int ct = 0; ct < 5; ++ct)
      #pragma unroll
      for (int rt = 0; rt < 4; ++rt)
        #pragma unroll
        for (int j = 0; j < 4; ++j)
          outs[(rt * 16 + l4 * 4 + j) * 321 + cb + ct * 16 + l15] += acc[rt][ct][j];
  }
  __syncthreads();

  // ---- write num + cat blocks (contiguous float4, NT) ----
  {
    constexpr int cards[13] = {32,10,20,15,8,30,12,5,25,6,40,18,9};
    constexpr int cbase[13] = {0,32,42,62,77,85,115,127,132,157,163,203,221};
    #pragma unroll
    for (int blk = 0; blk < 13; ++blk) {
      const int card = cards[blk];
      const int cbs  = cbase[blk];
      float* gout = out + (size_t)B_ROWS * cbs + (size_t)r0 * card;
      for (int v = tid; v < card * 16; v += 512) {
        int gg = v * 4;
        f32x4v vbuf;
        #pragma unroll
        for (int e = 0; e < 4; ++e) {
          int ge = gg + e;
          int brow = ge / card;
          int j = ge - brow * card;
          vbuf[e] = outs[brow * 321 + cbs + j];
        }
        __builtin_nontemporal_store(vbuf, (f32x4v*)(gout + gg));
      }
    }
  }

  // ---- gumbel-sigmoid heads (fast hw transcendentals) ----
  {
    int c = 230 + (tid >> 3);
    unsigned ka, kb; int Nh, head;
    if (c < 238)      { ka = NK0.a; kb = NK0.b; Nh = 8;  head = c - 230; }
    else if (c < 240) { ka = NK1.a; kb = NK1.b; Nh = 2;  head = c - 238; }
    else              { ka = NK2.a; kb = NK2.b; Nh = 54; head = c - 240; }
    #pragma unroll
    for (int q = 0; q < 2; ++q) {
      int rq = (tid & 7) * 4 + q * 32;
      f32x4v vbuf;
      #pragma unroll
      for (int e = 0; e < 4; ++e) {
        int rl = rq + e;
        float x = outs[rl * 321 + c];
        unsigned j = (unsigned)((r0 + rl) * Nh + head);
        TF2 t = threefry2x32(ka, kb, 0u, j);
        unsigned bits = t.a ^ t.b;
        float u  = __uint_as_float((bits >> 9) | 0x3f800000u) - 1.0f;
        float gn = -__logf(-__logf(u + 1e-20f) + 1e-20f);
        vbuf[e] = 1.0f / (1.0f + __expf(-(x + gn)));
      }
      __builtin_nontemporal_store(vbuf, (f32x4v*)(out + (size_t)B_ROWS * c + r0 + rq));
    }
  }
}

// ---------------- launch ----------------
extern "C" void kernel_launch(void* const* d_in, const int* in_sizes, int n_in,
                              void* d_out, int out_size, void* d_ws, size_t ws_size,
                              hipStream_t stream) {
  const float* z     = (const float*)d_in[0];
  const float* W1    = (const float*)d_in[1];
  const float* b1    = (const float*)d_in[2];
  const float* Wnum  = (const float*)d_in[3];
  const float* bnum  = (const float*)d_in[4];
  const float* Wcat  = (const float*)d_in[5];
  const float* bcat  = (const float*)d_in[6];
  const float* Wbin  = (const float*)d_in[7];
  const float* bbin  = (const float*)d_in[8];
  const float* Wlike = (const float*)d_in[9];
  const float* blike = (const float*)d_in[10];
  const float* Wmask = (const float*)d_in[11];
  const float* bmask = (const float*)d_in[12];

  unsigned short* W1p   = (unsigned short*)d_ws;            // 131072 bf16 = 256 KB
  unsigned short* Wallp = W1p + 131072;                     // 327680 bf16 = 640 KB
  float*          ball  = (float*)(Wallp + 327680);         // 320 f32

  prep_kernel<<<225, 256, 0, stream>>>(
      W1, Wnum, Wcat, Wbin, Wlike, Wmask, bnum, bcat, bbin, blike, bmask,
      W1p, Wallp, ball);

  decoder_kernel<<<B_ROWS / 64, 512, 0, stream>>>(
      z, b1, W1p, Wallp, ball, (float*)d_out);
}

// Round 15
// 29.159 us; speedup vs baseline: 1.0481x; 1.0481x over previous
//
#include <hip/hip_runtime.h>
#include <stdint.h>

// ---------------- problem constants ----------------
#define B_ROWS 16384
#define LATD   128
#define HIDD   1024

typedef __bf16 bf16x8 __attribute__((ext_vector_type(8)));
typedef float  f32x4  __attribute__((ext_vector_type(4)));
typedef float  f32x4v __attribute__((ext_vector_type(4)));
typedef unsigned short ushort8v __attribute__((ext_vector_type(8)));
typedef unsigned int   uint2v   __attribute__((ext_vector_type(2)));

// ---------------- asm helpers: unsinkable weight loads + counted waits ----------------
template<int N> __device__ __forceinline__ void waitv() {
  asm volatile("s_waitcnt vmcnt(%0)" :: "i"(N) : "memory");
  __builtin_amdgcn_sched_barrier(0);   // rule-18: no MFMA may hoist above the wait
}
__device__ __forceinline__ void gl16(bf16x8& r, const unsigned short* p) {
  asm volatile("global_load_dwordx4 %0, %1, off" : "=v"(r) : "v"(p));
}
template<int OFF> __device__ __forceinline__ void gl16o(bf16x8& r, const unsigned short* p) {
  asm volatile("global_load_dwordx4 %0, %1, off offset:%2" : "=v"(r) : "v"(p), "i"(OFF));
}
// barrier that drains LDS ops only — asm weight loads stay in flight
#define LGKM_BARRIER() do {                                        \
    asm volatile("s_waitcnt lgkmcnt(0)" ::: "memory");             \
    __builtin_amdgcn_s_barrier();                                  \
    asm volatile("" ::: "memory");                                 \
  } while (0)

// ---------------- threefry2x32 (matches JAX, partitionable default) ----------------
struct TF2 { unsigned int a, b; };

#define TF_R(x0,x1,r) { x0 += x1; x1 = ((x1 << (r)) | (x1 >> (32 - (r)))); x1 ^= x0; }

__host__ __device__ constexpr TF2 threefry2x32(unsigned k0, unsigned k1, unsigned c0, unsigned c1) {
  unsigned ks2 = k0 ^ k1 ^ 0x1BD11BDAu;
  unsigned x0 = c0 + k0, x1 = c1 + k1;
  TF_R(x0,x1,13) TF_R(x0,x1,15) TF_R(x0,x1,26) TF_R(x0,x1,6)
  x0 += k1;  x1 += ks2 + 1u;
  TF_R(x0,x1,17) TF_R(x0,x1,29) TF_R(x0,x1,16) TF_R(x0,x1,24)
  x0 += ks2; x1 += k0 + 2u;
  TF_R(x0,x1,13) TF_R(x0,x1,15) TF_R(x0,x1,26) TF_R(x0,x1,6)
  x0 += k0;  x1 += k1 + 3u;
  TF_R(x0,x1,17) TF_R(x0,x1,29) TF_R(x0,x1,16) TF_R(x0,x1,24)
  x0 += k1;  x1 += ks2 + 4u;
  TF_R(x0,x1,13) TF_R(x0,x1,15) TF_R(x0,x1,26) TF_R(x0,x1,6)
  x0 += ks2; x1 += k0 + 5u;
  return {x0, x1};
}

constexpr TF2 NK0 = threefry2x32(0u, 1u, 0u, 0u);  // bin heads
constexpr TF2 NK1 = threefry2x32(0u, 1u, 0u, 1u);  // like heads
constexpr TF2 NK2 = threefry2x32(0u, 1u, 0u, 2u);  // mask heads

__device__ __forceinline__ unsigned short f2bf(float f) {
  unsigned u = __float_as_uint(f);
  return (unsigned short)((u + 0x7fffu + ((u >> 16) & 1u)) >> 16);
}

// ---------------- prep v4: v3 + NT (write-through) output stores ----------------
// prep rewrites W1p/Wallp every replay; plain stores leave them DIRTY in the
// writing XCD's L2, so the other 7 XCDs' decoder WGs pull through the slow
// cross-XCD path each replay (the measured 8.6 us cold-warm gap). NT stores
// publish to L3 so all XCDs read the 1.2 MB package fast.
__global__ __launch_bounds__(256) void prep_kernel(
    const float* __restrict__ W1,
    const float* __restrict__ Wnum, const float* __restrict__ Wcat,
    const float* __restrict__ Wbin, const float* __restrict__ Wlike,
    const float* __restrict__ Wmask,
    const float* __restrict__ bnum, const float* __restrict__ bcat,
    const float* __restrict__ bbin, const float* __restrict__ blike,
    const float* __restrict__ bmask,
    unsigned short* __restrict__ W1p,
    unsigned short* __restrict__ Wallp,
    float* __restrict__ ball) {
  __shared__ __align__(16) unsigned short lds[16 * 136];
  const int b = blockIdx.x, t = threadIdx.x;

  if (b < 64) {
    const int n0 = b * 16;
    const int nq = t & 15;
    float v[8];
    #pragma unroll
    for (int i = 0; i < 8; ++i) {
      int k = i * 16 + (t >> 4);
      v[i] = W1[(size_t)k * HIDD + n0 + nq];
    }
    #pragma unroll
    for (int i = 0; i < 8; ++i) {
      int k = i * 16 + (t >> 4);
      lds[nq * 136 + k] = f2bf(v[i]);
    }
    __syncthreads();
    const int ks = t >> 6, l = t & 63;
    const int l15 = l & 15, l4 = (l >> 4);
    ushort8v p = *(const ushort8v*)(lds + l15 * 136 + ks * 32 + l4 * 8);
    __builtin_nontemporal_store(p, (ushort8v*)(W1p + ((size_t)(b * 4 + ks) * 64 + l) * 8));
  } else if (b < 224) {
    const int q  = b - 64;
    const int nt = q >> 3, kb = q & 7;
    const int n0 = nt * 16, k0 = kb * 128;
    const int n = n0 + (t & 15);
    const float* src = nullptr; int stride = 0;
    if (n < 32)       { src = Wnum  + n;         stride = 32;  }
    else if (n < 230) { src = Wcat  + (n - 32);  stride = 198; }
    else if (n < 238) { src = Wbin  + (n - 230); stride = 8;   }
    else if (n < 240) { src = Wlike + (n - 238); stride = 2;   }
    else if (n < 294) { src = Wmask + (n - 240); stride = 54;  }
    float v[8];
    if (src) {
      #pragma unroll
      for (int i = 0; i < 8; ++i) {
        int kk_loc = i * 16 + (t >> 4);
        v[i] = src[(size_t)(k0 + kk_loc) * stride];
      }
    } else {
      #pragma unroll
      for (int i = 0; i < 8; ++i) v[i] = 0.f;
    }
    #pragma unroll
    for (int i = 0; i < 8; ++i) {
      int kk_loc = i * 16 + (t >> 4);
      lds[(t & 15) * 136 + kk_loc] = f2bf(v[i]);
    }
    __syncthreads();
    const int kt_loc = t >> 6, l = t & 63;
    const int l15 = l & 15, l4 = (l >> 4);
    ushort8v p = *(const ushort8v*)(lds + l15 * 136 + kt_loc * 32 + l4 * 8);
    const int g = nt * 32 + kb * 4 + kt_loc;
    __builtin_nontemporal_store(p, (ushort8v*)(Wallp + ((size_t)g * 64 + l) * 8));
  } else {
    for (int n = t; n < 320; n += 256) {
      float v = 0.f;
      if (n < 32)       v = bnum [n];
      else if (n < 230) v = bcat [n - 32];
      else if (n < 238) v = bbin [n - 230];
      else if (n < 240) v = blike[n - 238];
      else if (n < 294) v = bmask[n - 240];
      __builtin_nontemporal_store(v, ball + n);
    }
  }
}

// ---------------- two-phase fused decoder core (EXACT r13 structure) ----------------
template<int G>
__device__ __forceinline__ void run_phases(
    const int w, const int lane, const int l15, const int l4, const int nt0,
    const unsigned short* __restrict__ W1p, const unsigned short* __restrict__ Wallp,
    const float* __restrict__ b1,
    unsigned char* smem, f32x4 (&acc)[4][3]) {

  constexpr int RING = (G == 3) ? 6 : 8;   // wq2 VGPR: G=3: 72, G=2: 64

  unsigned short* zs = (unsigned short*)smem;          // [64][136] bf16
  unsigned char* hbase  = smem + 17408;                // 8 x 16 KB h tiles
  unsigned char* mytile = hbase + w * 16384;

  f32x4 hb1[8];
  #pragma unroll
  for (int ct = 0; ct < 8; ++ct)
    hb1[ct] = *(const f32x4*)(b1 + w * 128 + ct * 16 + l4 * 4);

  bf16x8 za[4][4];
  #pragma unroll
  for (int rt = 0; rt < 4; ++rt)
    #pragma unroll
    for (int ks = 0; ks < 4; ++ks)
      za[rt][ks] = *(const bf16x8*)(zs + (rt * 16 + l15) * 136 + ks * 32 + l4 * 8);

  bf16x8 wq1[2][4];
  const unsigned short* w1b = W1p + (size_t)w * 16384 + lane * 8;
  #pragma unroll
  for (int ct = 0; ct < 2; ++ct) {
    const unsigned short* p = w1b + ct * 2048;
    gl16o<0>(wq1[ct][0], p); gl16o<1024>(wq1[ct][1], p);
    gl16o<2048>(wq1[ct][2], p); gl16o<3072>(wq1[ct][3], p);
  }

  bf16x8 wq2[RING][G];
  const unsigned short* w2b = Wallp + lane * 8;

  // ---- phase 1 ----
  #pragma unroll
  for (int ct = 0; ct < 8; ++ct) {
    if (ct < 7) waitv<4>();
    else        waitv<G * RING>();   // wq1 g7 arrived; all RING wq2 groups in flight
    f32x4 a[4] = {};
    #pragma unroll
    for (int ks = 0; ks < 4; ++ks)
      #pragma unroll
      for (int rt = 0; rt < 4; ++rt)
        a[rt] = __builtin_amdgcn_mfma_f32_16x16x32_bf16(wq1[ct & 1][ks], za[rt][ks], a[rt], 0, 0, 0);
    #pragma unroll
    for (int rt = 0; rt < 4; ++rt) {
      float v0 = fmaxf(a[rt][0] + hb1[ct][0], 0.f);
      float v1 = fmaxf(a[rt][1] + hb1[ct][1], 0.f);
      float v2 = fmaxf(a[rt][2] + hb1[ct][2], 0.f);
      float v3 = fmaxf(a[rt][3] + hb1[ct][3], 0.f);
      uint2v u;
      u[0] = (unsigned)f2bf(v0) | ((unsigned)f2bf(v1) << 16);
      u[1] = (unsigned)f2bf(v2) | ((unsigned)f2bf(v3) << 16);
      const int byte = ((ct >> 1) * 4 + rt) * 1024
                     + ((ct & 1) * 2 + (l4 >> 1)) * 256
                     + l15 * 16 + (l4 & 1) * 8;
      *(uint2v*)(mytile + byte) = u;
    }
    if (ct < 6) {
      const unsigned short* p = w1b + (ct + 2) * 2048;
      gl16o<0>(wq1[ct & 1][0], p); gl16o<1024>(wq1[ct & 1][1], p);
      gl16o<2048>(wq1[ct & 1][2], p); gl16o<3072>(wq1[ct & 1][3], p);
    } else if (ct == 6) {
      #pragma unroll
      for (int g = 0; g < RING; ++g)
        #pragma unroll
        for (int cc = 0; cc < G; ++cc)
          gl16(wq2[g][cc], w2b + (size_t)((nt0 + cc) * 32 + g) * 512);
    }
  }

  LGKM_BARRIER();    // h visible to all waves; weight prefetches stay in flight

  // ---- phase 2 ----
  #pragma unroll
  for (int rt = 0; rt < 4; ++rt)
    #pragma unroll
    for (int ct = 0; ct < 3; ++ct)
      acc[rt][ct] = (f32x4){0.f, 0.f, 0.f, 0.f};

  #pragma unroll
  for (int g = 0; g < 32; ++g) {
    const int rem = 31 - g;          // constant after unroll
    if (rem >= RING - 1)  waitv<G * (RING - 1)>();
    else if (rem == 6)    waitv<G * 6>();
    else if (rem == 5)    waitv<G * 5>();
    else if (rem == 4)    waitv<G * 4>();
    else if (rem == 3)    waitv<G * 3>();
    else if (rem == 2)    waitv<G * 2>();
    else if (rem == 1)    waitv<G * 1>();
    else                  waitv<0>();
    const unsigned char* hc = hbase + (g >> 2) * 16384 + (g & 3) * 4096 + lane * 16;
    #pragma unroll
    for (int rt = 0; rt < 4; ++rt) {
      bf16x8 ha = *(const bf16x8*)(hc + rt * 1024);
      #pragma unroll
      for (int ct = 0; ct < G; ++ct)
        acc[rt][ct] = __builtin_amdgcn_mfma_f32_16x16x32_bf16(ha, wq2[g % RING][ct], acc[rt][ct], 0, 0, 0);
    }
    if (g + RING < 32) {
      #pragma unroll
      for (int cc = 0; cc < G; ++cc)
        gl16(wq2[g % RING][cc], w2b + (size_t)((nt0 + cc) * 32 + (g + RING)) * 512);
    }
  }
}

// ---------------- main kernel: 256 WGs x 512 thr (8 waves), 64 rows/WG ----------------
__global__ __launch_bounds__(512, 2) void decoder_kernel(
    const float* __restrict__ z, const float* __restrict__ b1,
    const unsigned short* __restrict__ W1p, const unsigned short* __restrict__ Wallp,
    const float* __restrict__ ball, float* __restrict__ out) {
  __shared__ __align__(16) unsigned char smem[148480];
  unsigned short* zs = (unsigned short*)smem;
  float* outs = (float*)smem;

  const int tid  = threadIdx.x;
  const int lane = tid & 63;
  const int w    = tid >> 6;
  const int l15  = lane & 15;
  const int l4   = lane >> 4;
  const int r0   = blockIdx.x * 64;

  #pragma unroll
  for (int it = 0; it < 2; ++it) {
    int ch  = tid + it * 512;
    int row = ch >> 4;
    int k0  = (ch & 15) * 8;
    const float* src = z + (size_t)(r0 + row) * LATD + k0;
    f32x4v f0 = __builtin_nontemporal_load((const f32x4v*)src);
    f32x4v f1 = __builtin_nontemporal_load((const f32x4v*)(src + 4));
    ushort8v p;
    p[0] = f2bf(f0[0]); p[1] = f2bf(f0[1]); p[2] = f2bf(f0[2]); p[3] = f2bf(f0[3]);
    p[4] = f2bf(f1[0]); p[5] = f2bf(f1[1]); p[6] = f2bf(f1[2]); p[7] = f2bf(f1[3]);
    *(ushort8v*)(zs + row * 136 + k0) = p;
  }
  __syncthreads();   // full drain OK: no asm loads issued yet

  const int cb  = (w < 4) ? w * 48 : 192 + (w - 4) * 32;
  const int nt0 = (w < 4) ? w * 3  : 12 + (w - 4) * 2;
  const int myG = (w < 4) ? 3 : 2;

  f32x4 acc[4][3];
  if (w < 4) run_phases<3>(w, lane, l15, l4, nt0, W1p, Wallp, b1, smem, acc);
  else       run_phases<2>(w, lane, l15, l4, nt0, W1p, Wallp, b1, smem, acc);

  __syncthreads();   // all h reads done; LDS becomes outs

  #pragma unroll
  for (int ct = 0; ct < 3; ++ct) {
    if (ct < myG) {
      float b2 = ball[cb + ct * 16 + l15];
      #pragma unroll
      for (int rt = 0; rt < 4; ++rt)
        #pragma unroll
        for (int j = 0; j < 4; ++j)
          outs[(rt * 16 + l4 * 4 + j) * 321 + cb + ct * 16 + l15] = acc[rt][ct][j] + b2;
    }
  }
  __syncthreads();

  {
    constexpr int cards[13] = {32,10,20,15,8,30,12,5,25,6,40,18,9};
    constexpr int cbase[13] = {0,32,42,62,77,85,115,127,132,157,163,203,221};
    #pragma unroll
    for (int blk = 0; blk < 13; ++blk) {
      const int card = cards[blk];
      const int cbs  = cbase[blk];
      float* gout = out + (size_t)B_ROWS * cbs + (size_t)r0 * card;
      for (int v = tid; v < card * 16; v += 512) {
        int gg = v * 4;
        f32x4v vbuf;
        #pragma unroll
        for (int e = 0; e < 4; ++e) {
          int ge = gg + e;
          int brow = ge / card;
          int j = ge - brow * card;
          vbuf[e] = outs[brow * 321 + cbs + j];
        }
        __builtin_nontemporal_store(vbuf, (f32x4v*)(gout + gg));
      }
    }
  }

  {
    int c = 230 + (tid >> 3);
    unsigned ka, kb; int Nh, head;
    if (c < 238)      { ka = NK0.a; kb = NK0.b; Nh = 8;  head = c - 230; }
    else if (c < 240) { ka = NK1.a; kb = NK1.b; Nh = 2;  head = c - 238; }
    else              { ka = NK2.a; kb = NK2.b; Nh = 54; head = c - 240; }
    #pragma unroll
    for (int q = 0; q < 2; ++q) {
      int rq = (tid & 7) * 4 + q * 32;
      f32x4v vbuf;
      #pragma unroll
      for (int e = 0; e < 4; ++e) {
        int rl = rq + e;
        float x = outs[rl * 321 + c];
        unsigned j = (unsigned)((r0 + rl) * Nh + head);
        TF2 t = threefry2x32(ka, kb, 0u, j);
        unsigned bits = t.a ^ t.b;
        float u  = __uint_as_float((bits >> 9) | 0x3f800000u) - 1.0f;
        float gn = -__logf(-__logf(u + 1e-20f) + 1e-20f);
        vbuf[e] = 1.0f / (1.0f + __expf(-(x + gn)));
      }
      __builtin_nontemporal_store(vbuf, (f32x4v*)(out + (size_t)B_ROWS * c + r0 + rq));
    }
  }
}

// ---------------- launch ----------------
extern "C" void kernel_launch(void* const* d_in, const int* in_sizes, int n_in,
                              void* d_out, int out_size, void* d_ws, size_t ws_size,
                              hipStream_t stream) {
  const float* z     = (const float*)d_in[0];
  const float* W1    = (const float*)d_in[1];
  const float* b1    = (const float*)d_in[2];
  const float* Wnum  = (const float*)d_in[3];
  const float* bnum  = (const float*)d_in[4];
  const float* Wcat  = (const float*)d_in[5];
  const float* bcat  = (const float*)d_in[6];
  const float* Wbin  = (const float*)d_in[7];
  const float* bbin  = (const float*)d_in[8];
  const float* Wlike = (const float*)d_in[9];
  const float* blike = (const float*)d_in[10];
  const float* Wmask = (const float*)d_in[11];
  const float* bmask = (const float*)d_in[12];

  unsigned short* W1p   = (unsigned short*)d_ws;            // 131072 bf16 = 256 KB
  unsigned short* Wallp = W1p + 131072;                     // 327680 bf16 = 640 KB
  float*          ball  = (float*)(Wallp + 327680);         // 320 f32

  prep_kernel<<<225, 256, 0, stream>>>(
      W1, Wnum, Wcat, Wbin, Wlike, Wmask, bnum, bcat, bbin, blike, bmask,
      W1p, Wallp, ball);

  decoder_kernel<<<B_ROWS / 64, 512, 0, stream>>>(
      z, b1, W1p, Wallp, ball, (float*)d_out);
}

// Round 16
// 28.909 us; speedup vs baseline: 1.0572x; 1.0087x over previous
//
#include <hip/hip_runtime.h>
#include <stdint.h>

// ---------------- problem constants ----------------
#define B_ROWS 16384
#define LATD   128
#define HIDD   1024

typedef __bf16 bf16x8 __attribute__((ext_vector_type(8)));
typedef float  f32x4  __attribute__((ext_vector_type(4)));
typedef float  f32x4v __attribute__((ext_vector_type(4)));
typedef unsigned short ushort8v __attribute__((ext_vector_type(8)));
typedef unsigned int   uint2v   __attribute__((ext_vector_type(2)));

// ---------------- asm helpers: unsinkable weight loads + counted waits ----------------
template<int N> __device__ __forceinline__ void waitv() {
  asm volatile("s_waitcnt vmcnt(%0)" :: "i"(N) : "memory");
  __builtin_amdgcn_sched_barrier(0);   // rule-18: no MFMA may hoist above the wait
}
__device__ __forceinline__ void gl16(bf16x8& r, const unsigned short* p) {
  asm volatile("global_load_dwordx4 %0, %1, off" : "=v"(r) : "v"(p));
}
template<int OFF> __device__ __forceinline__ void gl16o(bf16x8& r, const unsigned short* p) {
  asm volatile("global_load_dwordx4 %0, %1, off offset:%2" : "=v"(r) : "v"(p), "i"(OFF));
}
// barrier that drains LDS ops only — asm weight loads stay in flight
#define LGKM_BARRIER() do {                                        \
    asm volatile("s_waitcnt lgkmcnt(0)" ::: "memory");             \
    __builtin_amdgcn_s_barrier();                                  \
    asm volatile("" ::: "memory");                                 \
  } while (0)

// ---------------- threefry2x32 (matches JAX, partitionable default) ----------------
struct TF2 { unsigned int a, b; };

#define TF_R(x0,x1,r) { x0 += x1; x1 = ((x1 << (r)) | (x1 >> (32 - (r)))); x1 ^= x0; }

__host__ __device__ constexpr TF2 threefry2x32(unsigned k0, unsigned k1, unsigned c0, unsigned c1) {
  unsigned ks2 = k0 ^ k1 ^ 0x1BD11BDAu;
  unsigned x0 = c0 + k0, x1 = c1 + k1;
  TF_R(x0,x1,13) TF_R(x0,x1,15) TF_R(x0,x1,26) TF_R(x0,x1,6)
  x0 += k1;  x1 += ks2 + 1u;
  TF_R(x0,x1,17) TF_R(x0,x1,29) TF_R(x0,x1,16) TF_R(x0,x1,24)
  x0 += ks2; x1 += k0 + 2u;
  TF_R(x0,x1,13) TF_R(x0,x1,15) TF_R(x0,x1,26) TF_R(x0,x1,6)
  x0 += k0;  x1 += k1 + 3u;
  TF_R(x0,x1,17) TF_R(x0,x1,29) TF_R(x0,x1,16) TF_R(x0,x1,24)
  x0 += k1;  x1 += ks2 + 4u;
  TF_R(x0,x1,13) TF_R(x0,x1,15) TF_R(x0,x1,26) TF_R(x0,x1,6)
  x0 += ks2; x1 += k0 + 5u;
  return {x0, x1};
}

constexpr TF2 NK0 = threefry2x32(0u, 1u, 0u, 0u);  // bin heads
constexpr TF2 NK1 = threefry2x32(0u, 1u, 0u, 1u);  // like heads
constexpr TF2 NK2 = threefry2x32(0u, 1u, 0u, 2u);  // mask heads

__device__ __forceinline__ unsigned short f2bf(float f) {
  unsigned u = __float_as_uint(f);
  return (unsigned short)((u + 0x7fffu + ((u >> 16) & 1u)) >> 16);
}

// ---------------- prep v4 (r15, kept) ----------------
__global__ __launch_bounds__(256) void prep_kernel(
    const float* __restrict__ W1,
    const float* __restrict__ Wnum, const float* __restrict__ Wcat,
    const float* __restrict__ Wbin, const float* __restrict__ Wlike,
    const float* __restrict__ Wmask,
    const float* __restrict__ bnum, const float* __restrict__ bcat,
    const float* __restrict__ bbin, const float* __restrict__ blike,
    const float* __restrict__ bmask,
    unsigned short* __restrict__ W1p,
    unsigned short* __restrict__ Wallp,
    float* __restrict__ ball) {
  __shared__ __align__(16) unsigned short lds[16 * 136];
  const int b = blockIdx.x, t = threadIdx.x;

  if (b < 64) {
    const int n0 = b * 16;
    const int nq = t & 15;
    float v[8];
    #pragma unroll
    for (int i = 0; i < 8; ++i) {
      int k = i * 16 + (t >> 4);
      v[i] = W1[(size_t)k * HIDD + n0 + nq];
    }
    #pragma unroll
    for (int i = 0; i < 8; ++i) {
      int k = i * 16 + (t >> 4);
      lds[nq * 136 + k] = f2bf(v[i]);
    }
    __syncthreads();
    const int ks = t >> 6, l = t & 63;
    const int l15 = l & 15, l4 = (l >> 4);
    ushort8v p = *(const ushort8v*)(lds + l15 * 136 + ks * 32 + l4 * 8);
    __builtin_nontemporal_store(p, (ushort8v*)(W1p + ((size_t)(b * 4 + ks) * 64 + l) * 8));
  } else if (b < 224) {
    const int q  = b - 64;
    const int nt = q >> 3, kb = q & 7;
    const int n0 = nt * 16, k0 = kb * 128;
    const int n = n0 + (t & 15);
    const float* src = nullptr; int stride = 0;
    if (n < 32)       { src = Wnum  + n;         stride = 32;  }
    else if (n < 230) { src = Wcat  + (n - 32);  stride = 198; }
    else if (n < 238) { src = Wbin  + (n - 230); stride = 8;   }
    else if (n < 240) { src = Wlike + (n - 238); stride = 2;   }
    else if (n < 294) { src = Wmask + (n - 240); stride = 54;  }
    float v[8];
    if (src) {
      #pragma unroll
      for (int i = 0; i < 8; ++i) {
        int kk_loc = i * 16 + (t >> 4);
        v[i] = src[(size_t)(k0 + kk_loc) * stride];
      }
    } else {
      #pragma unroll
      for (int i = 0; i < 8; ++i) v[i] = 0.f;
    }
    #pragma unroll
    for (int i = 0; i < 8; ++i) {
      int kk_loc = i * 16 + (t >> 4);
      lds[(t & 15) * 136 + kk_loc] = f2bf(v[i]);
    }
    __syncthreads();
    const int kt_loc = t >> 6, l = t & 63;
    const int l15 = l & 15, l4 = (l >> 4);
    ushort8v p = *(const ushort8v*)(lds + l15 * 136 + kt_loc * 32 + l4 * 8);
    const int g = nt * 32 + kb * 4 + kt_loc;
    __builtin_nontemporal_store(p, (ushort8v*)(Wallp + ((size_t)g * 64 + l) * 8));
  } else {
    for (int n = t; n < 320; n += 256) {
      float v = 0.f;
      if (n < 32)       v = bnum [n];
      else if (n < 230) v = bcat [n - 32];
      else if (n < 238) v = bbin [n - 230];
      else if (n < 240) v = blike[n - 238];
      else if (n < 294) v = bmask[n - 240];
      __builtin_nontemporal_store(v, ball + n);
    }
  }
}

// ---------------- two-phase fused decoder core (EXACT r13 structure) ----------------
template<int G>
__device__ __forceinline__ void run_phases(
    const int w, const int lane, const int l15, const int l4, const int nt0,
    const unsigned short* __restrict__ W1p, const unsigned short* __restrict__ Wallp,
    const float* __restrict__ b1,
    unsigned char* smem, f32x4 (&acc)[4][3]) {

  constexpr int RING = (G == 3) ? 6 : 8;   // wq2 VGPR: G=3: 72, G=2: 64

  unsigned short* zs = (unsigned short*)smem;          // [64][136] bf16
  unsigned char* hbase  = smem + 17408;                // 8 x 16 KB h tiles
  unsigned char* mytile = hbase + w * 16384;

  f32x4 hb1[8];
  #pragma unroll
  for (int ct = 0; ct < 8; ++ct)
    hb1[ct] = *(const f32x4*)(b1 + w * 128 + ct * 16 + l4 * 4);

  bf16x8 za[4][4];
  #pragma unroll
  for (int rt = 0; rt < 4; ++rt)
    #pragma unroll
    for (int ks = 0; ks < 4; ++ks)
      za[rt][ks] = *(const bf16x8*)(zs + (rt * 16 + l15) * 136 + ks * 32 + l4 * 8);

  bf16x8 wq1[2][4];
  const unsigned short* w1b = W1p + (size_t)w * 16384 + lane * 8;
  #pragma unroll
  for (int ct = 0; ct < 2; ++ct) {
    const unsigned short* p = w1b + ct * 2048;
    gl16o<0>(wq1[ct][0], p); gl16o<1024>(wq1[ct][1], p);
    gl16o<2048>(wq1[ct][2], p); gl16o<3072>(wq1[ct][3], p);
  }

  bf16x8 wq2[RING][G];
  const unsigned short* w2b = Wallp + lane * 8;

  // ---- phase 1 ----
  #pragma unroll
  for (int ct = 0; ct < 8; ++ct) {
    if (ct < 7) waitv<4>();
    else        waitv<G * RING>();   // wq1 g7 arrived; all RING wq2 groups in flight
    f32x4 a[4] = {};
    #pragma unroll
    for (int ks = 0; ks < 4; ++ks)
      #pragma unroll
      for (int rt = 0; rt < 4; ++rt)
        a[rt] = __builtin_amdgcn_mfma_f32_16x16x32_bf16(wq1[ct & 1][ks], za[rt][ks], a[rt], 0, 0, 0);
    #pragma unroll
    for (int rt = 0; rt < 4; ++rt) {
      float v0 = fmaxf(a[rt][0] + hb1[ct][0], 0.f);
      float v1 = fmaxf(a[rt][1] + hb1[ct][1], 0.f);
      float v2 = fmaxf(a[rt][2] + hb1[ct][2], 0.f);
      float v3 = fmaxf(a[rt][3] + hb1[ct][3], 0.f);
      uint2v u;
      u[0] = (unsigned)f2bf(v0) | ((unsigned)f2bf(v1) << 16);
      u[1] = (unsigned)f2bf(v2) | ((unsigned)f2bf(v3) << 16);
      const int byte = ((ct >> 1) * 4 + rt) * 1024
                     + ((ct & 1) * 2 + (l4 >> 1)) * 256
                     + l15 * 16 + (l4 & 1) * 8;
      *(uint2v*)(mytile + byte) = u;
    }
    if (ct < 6) {
      const unsigned short* p = w1b + (ct + 2) * 2048;
      gl16o<0>(wq1[ct & 1][0], p); gl16o<1024>(wq1[ct & 1][1], p);
      gl16o<2048>(wq1[ct & 1][2], p); gl16o<3072>(wq1[ct & 1][3], p);
    } else if (ct == 6) {
      #pragma unroll
      for (int g = 0; g < RING; ++g)
        #pragma unroll
        for (int cc = 0; cc < G; ++cc)
          gl16(wq2[g][cc], w2b + (size_t)((nt0 + cc) * 32 + g) * 512);
    }
  }

  LGKM_BARRIER();    // h visible to all waves; weight prefetches stay in flight

  // ---- phase 2 ----
  #pragma unroll
  for (int rt = 0; rt < 4; ++rt)
    #pragma unroll
    for (int ct = 0; ct < 3; ++ct)
      acc[rt][ct] = (f32x4){0.f, 0.f, 0.f, 0.f};

  #pragma unroll
  for (int g = 0; g < 32; ++g) {
    const int rem = 31 - g;          // constant after unroll
    if (rem >= RING - 1)  waitv<G * (RING - 1)>();
    else if (rem == 6)    waitv<G * 6>();
    else if (rem == 5)    waitv<G * 5>();
    else if (rem == 4)    waitv<G * 4>();
    else if (rem == 3)    waitv<G * 3>();
    else if (rem == 2)    waitv<G * 2>();
    else if (rem == 1)    waitv<G * 1>();
    else                  waitv<0>();
    const unsigned char* hc = hbase + (g >> 2) * 16384 + (g & 3) * 4096 + lane * 16;
    #pragma unroll
    for (int rt = 0; rt < 4; ++rt) {
      bf16x8 ha = *(const bf16x8*)(hc + rt * 1024);
      #pragma unroll
      for (int ct = 0; ct < G; ++ct)
        acc[rt][ct] = __builtin_amdgcn_mfma_f32_16x16x32_bf16(ha, wq2[g % RING][ct], acc[rt][ct], 0, 0, 0);
    }
    if (g + RING < 32) {
      #pragma unroll
      for (int cc = 0; cc < G; ++cc)
        gl16(wq2[g % RING][cc], w2b + (size_t)((nt0 + cc) * 32 + (g + RING)) * 512);
    }
  }
}

// ---------------- main kernel: 256 WGs x 512 thr (8 waves), 64 rows/WG ----------------
__global__ __launch_bounds__(512, 2) void decoder_kernel(
    const float* __restrict__ z, const float* __restrict__ b1,
    const unsigned short* __restrict__ W1p, const unsigned short* __restrict__ Wallp,
    const float* __restrict__ ball, float* __restrict__ out) {
  __shared__ __align__(16) unsigned char smem[148480];
  unsigned short* zs = (unsigned short*)smem;
  float* outs = (float*)smem;

  const int tid  = threadIdx.x;
  const int lane = tid & 63;
  const int w    = tid >> 6;
  const int l15  = lane & 15;
  const int l4   = lane >> 4;
  const int r0   = blockIdx.x * 64;

  // ---- stage z tile -> LDS bf16 (CACHED loads: z is 8 MB, per-XCD share ~1 MB —
  //      fits L2, persists across graph replays; NT here cost a cold HBM re-read
  //      of z every replay at the serial head of the kernel) ----
  #pragma unroll
  for (int it = 0; it < 2; ++it) {
    int ch  = tid + it * 512;
    int row = ch >> 4;
    int k0  = (ch & 15) * 8;
    const float* src = z + (size_t)(r0 + row) * LATD + k0;
    f32x4 f0 = *(const f32x4*)src;
    f32x4 f1 = *(const f32x4*)(src + 4);
    ushort8v p;
    p[0] = f2bf(f0[0]); p[1] = f2bf(f0[1]); p[2] = f2bf(f0[2]); p[3] = f2bf(f0[3]);
    p[4] = f2bf(f1[0]); p[5] = f2bf(f1[1]); p[6] = f2bf(f1[2]); p[7] = f2bf(f1[3]);
    *(ushort8v*)(zs + row * 136 + k0) = p;
  }
  __syncthreads();   // full drain OK: no asm loads issued yet

  const int cb  = (w < 4) ? w * 48 : 192 + (w - 4) * 32;
  const int nt0 = (w < 4) ? w * 3  : 12 + (w - 4) * 2;
  const int myG = (w < 4) ? 3 : 2;

  f32x4 acc[4][3];
  if (w < 4) run_phases<3>(w, lane, l15, l4, nt0, W1p, Wallp, b1, smem, acc);
  else       run_phases<2>(w, lane, l15, l4, nt0, W1p, Wallp, b1, smem, acc);

  __syncthreads();   // all h reads done; LDS becomes outs

  #pragma unroll
  for (int ct = 0; ct < 3; ++ct) {
    if (ct < myG) {
      float b2 = ball[cb + ct * 16 + l15];
      #pragma unroll
      for (int rt = 0; rt < 4; ++rt)
        #pragma unroll
        for (int j = 0; j < 4; ++j)
          outs[(rt * 16 + l4 * 4 + j) * 321 + cb + ct * 16 + l15] = acc[rt][ct][j] + b2;
    }
  }
  __syncthreads();

  {
    constexpr int cards[13] = {32,10,20,15,8,30,12,5,25,6,40,18,9};
    constexpr int cbase[13] = {0,32,42,62,77,85,115,127,132,157,163,203,221};
    #pragma unroll
    for (int blk = 0; blk < 13; ++blk) {
      const int card = cards[blk];
      const int cbs  = cbase[blk];
      float* gout = out + (size_t)B_ROWS * cbs + (size_t)r0 * card;
      for (int v = tid; v < card * 16; v += 512) {
        int gg = v * 4;
        f32x4v vbuf;
        #pragma unroll
        for (int e = 0; e < 4; ++e) {
          int ge = gg + e;
          int brow = ge / card;
          int j = ge - brow * card;
          vbuf[e] = outs[brow * 321 + cbs + j];
        }
        __builtin_nontemporal_store(vbuf, (f32x4v*)(gout + gg));
      }
    }
  }

  {
    int c = 230 + (tid >> 3);
    unsigned ka, kb; int Nh, head;
    if (c < 238)      { ka = NK0.a; kb = NK0.b; Nh = 8;  head = c - 230; }
    else if (c < 240) { ka = NK1.a; kb = NK1.b; Nh = 2;  head = c - 238; }
    else              { ka = NK2.a; kb = NK2.b; Nh = 54; head = c - 240; }
    #pragma unroll
    for (int q = 0; q < 2; ++q) {
      int rq = (tid & 7) * 4 + q * 32;
      f32x4v vbuf;
      #pragma unroll
      for (int e = 0; e < 4; ++e) {
        int rl = rq + e;
        float x = outs[rl * 321 + c];
        unsigned j = (unsigned)((r0 + rl) * Nh + head);
        TF2 t = threefry2x32(ka, kb, 0u, j);
        unsigned bits = t.a ^ t.b;
        float u  = __uint_as_float((bits >> 9) | 0x3f800000u) - 1.0f;
        float gn = -__logf(-__logf(u + 1e-20f) + 1e-20f);
        vbuf[e] = 1.0f / (1.0f + __expf(-(x + gn)));
      }
      __builtin_nontemporal_store(vbuf, (f32x4v*)(out + (size_t)B_ROWS * c + r0 + rq));
    }
  }
}

// ---------------- launch ----------------
extern "C" void kernel_launch(void* const* d_in, const int* in_sizes, int n_in,
                              void* d_out, int out_size, void* d_ws, size_t ws_size,
                              hipStream_t stream) {
  const float* z     = (const float*)d_in[0];
  const float* W1    = (const float*)d_in[1];
  const float* b1    = (const float*)d_in[2];
  const float* Wnum  = (const float*)d_in[3];
  const float* bnum  = (const float*)d_in[4];
  const float* Wcat  = (const float*)d_in[5];
  const float* bcat  = (const float*)d_in[6];
  const float* Wbin  = (const float*)d_in[7];
  const float* bbin  = (const float*)d_in[8];
  const float* Wlike = (const float*)d_in[9];
  const float* blike = (const float*)d_in[10];
  const float* Wmask = (const float*)d_in[11];
  const float* bmask = (const float*)d_in[12];

  unsigned short* W1p   = (unsigned short*)d_ws;            // 131072 bf16 = 256 KB
  unsigned short* Wallp = W1p + 131072;                     // 327680 bf16 = 640 KB
  float*          ball  = (float*)(Wallp + 327680);         // 320 f32

  prep_kernel<<<225, 256, 0, stream>>>(
      W1, Wnum, Wcat, Wbin, Wlike, Wmask, bnum, bcat, bbin, blike, bmask,
      W1p, Wallp, ball);

  decoder_kernel<<<B_ROWS / 64, 512, 0, stream>>>(
      z, b1, W1p, Wallp, ball, (float*)d_out);
}

// Round 17
// 28.504 us; speedup vs baseline: 1.0722x; 1.0142x over previous
//
#include <hip/hip_runtime.h>
#include <stdint.h>

// ---------------- problem constants ----------------
#define B_ROWS 16384
#define LATD   128
#define HIDD   1024

typedef __bf16 bf16x8 __attribute__((ext_vector_type(8)));
typedef float  f32x4  __attribute__((ext_vector_type(4)));
typedef float  f32x4v __attribute__((ext_vector_type(4)));
typedef unsigned short ushort8v __attribute__((ext_vector_type(8)));
typedef unsigned int   uint2v   __attribute__((ext_vector_type(2)));

// ---------------- asm helpers: unsinkable weight loads + counted waits ----------------
template<int N> __device__ __forceinline__ void waitv() {
  asm volatile("s_waitcnt vmcnt(%0)" :: "i"(N) : "memory");
  __builtin_amdgcn_sched_barrier(0);   // rule-18: no MFMA may hoist above the wait
}
__device__ __forceinline__ void gl16(bf16x8& r, const unsigned short* p) {
  asm volatile("global_load_dwordx4 %0, %1, off" : "=v"(r) : "v"(p));
}
template<int OFF> __device__ __forceinline__ void gl16o(bf16x8& r, const unsigned short* p) {
  asm volatile("global_load_dwordx4 %0, %1, off offset:%2" : "=v"(r) : "v"(p), "i"(OFF));
}
// barrier that drains LDS ops only — asm weight loads stay in flight
#define LGKM_BARRIER() do {                                        \
    asm volatile("s_waitcnt lgkmcnt(0)" ::: "memory");             \
    __builtin_amdgcn_s_barrier();                                  \
    asm volatile("" ::: "memory");                                 \
  } while (0)

// ---------------- threefry2x32 (matches JAX, partitionable default) ----------------
struct TF2 { unsigned int a, b; };

#define TF_R(x0,x1,r) { x0 += x1; x1 = ((x1 << (r)) | (x1 >> (32 - (r)))); x1 ^= x0; }

__host__ __device__ constexpr TF2 threefry2x32(unsigned k0, unsigned k1, unsigned c0, unsigned c1) {
  unsigned ks2 = k0 ^ k1 ^ 0x1BD11BDAu;
  unsigned x0 = c0 + k0, x1 = c1 + k1;
  TF_R(x0,x1,13) TF_R(x0,x1,15) TF_R(x0,x1,26) TF_R(x0,x1,6)
  x0 += k1;  x1 += ks2 + 1u;
  TF_R(x0,x1,17) TF_R(x0,x1,29) TF_R(x0,x1,16) TF_R(x0,x1,24)
  x0 += ks2; x1 += k0 + 2u;
  TF_R(x0,x1,13) TF_R(x0,x1,15) TF_R(x0,x1,26) TF_R(x0,x1,6)
  x0 += k0;  x1 += k1 + 3u;
  TF_R(x0,x1,17) TF_R(x0,x1,29) TF_R(x0,x1,16) TF_R(x0,x1,24)
  x0 += k1;  x1 += ks2 + 4u;
  TF_R(x0,x1,13) TF_R(x0,x1,15) TF_R(x0,x1,26) TF_R(x0,x1,6)
  x0 += ks2; x1 += k0 + 5u;
  return {x0, x1};
}

constexpr TF2 NK0 = threefry2x32(0u, 1u, 0u, 0u);  // bin heads
constexpr TF2 NK1 = threefry2x32(0u, 1u, 0u, 1u);  // like heads
constexpr TF2 NK2 = threefry2x32(0u, 1u, 0u, 2u);  // mask heads

__device__ __forceinline__ unsigned short f2bf(float f) {
  unsigned u = __float_as_uint(f);
  return (unsigned short)((u + 0x7fffu + ((u >> 16) & 1u)) >> 16);
}

// ---------------- prep v4 (r15, kept) ----------------
__global__ __launch_bounds__(256) void prep_kernel(
    const float* __restrict__ W1,
    const float* __restrict__ Wnum, const float* __restrict__ Wcat,
    const float* __restrict__ Wbin, const float* __restrict__ Wlike,
    const float* __restrict__ Wmask,
    const float* __restrict__ bnum, const float* __restrict__ bcat,
    const float* __restrict__ bbin, const float* __restrict__ blike,
    const float* __restrict__ bmask,
    unsigned short* __restrict__ W1p,
    unsigned short* __restrict__ Wallp,
    float* __restrict__ ball) {
  __shared__ __align__(16) unsigned short lds[16 * 136];
  const int b = blockIdx.x, t = threadIdx.x;

  if (b < 64) {
    const int n0 = b * 16;
    const int nq = t & 15;
    float v[8];
    #pragma unroll
    for (int i = 0; i < 8; ++i) {
      int k = i * 16 + (t >> 4);
      v[i] = W1[(size_t)k * HIDD + n0 + nq];
    }
    #pragma unroll
    for (int i = 0; i < 8; ++i) {
      int k = i * 16 + (t >> 4);
      lds[nq * 136 + k] = f2bf(v[i]);
    }
    __syncthreads();
    const int ks = t >> 6, l = t & 63;
    const int l15 = l & 15, l4 = (l >> 4);
    ushort8v p = *(const ushort8v*)(lds + l15 * 136 + ks * 32 + l4 * 8);
    __builtin_nontemporal_store(p, (ushort8v*)(W1p + ((size_t)(b * 4 + ks) * 64 + l) * 8));
  } else if (b < 224) {
    const int q  = b - 64;
    const int nt = q >> 3, kb = q & 7;
    const int n0 = nt * 16, k0 = kb * 128;
    const int n = n0 + (t & 15);
    const float* src = nullptr; int stride = 0;
    if (n < 32)       { src = Wnum  + n;         stride = 32;  }
    else if (n < 230) { src = Wcat  + (n - 32);  stride = 198; }
    else if (n < 238) { src = Wbin  + (n - 230); stride = 8;   }
    else if (n < 240) { src = Wlike + (n - 238); stride = 2;   }
    else if (n < 294) { src = Wmask + (n - 240); stride = 54;  }
    float v[8];
    if (src) {
      #pragma unroll
      for (int i = 0; i < 8; ++i) {
        int kk_loc = i * 16 + (t >> 4);
        v[i] = src[(size_t)(k0 + kk_loc) * stride];
      }
    } else {
      #pragma unroll
      for (int i = 0; i < 8; ++i) v[i] = 0.f;
    }
    #pragma unroll
    for (int i = 0; i < 8; ++i) {
      int kk_loc = i * 16 + (t >> 4);
      lds[(t & 15) * 136 + kk_loc] = f2bf(v[i]);
    }
    __syncthreads();
    const int kt_loc = t >> 6, l = t & 63;
    const int l15 = l & 15, l4 = (l >> 4);
    ushort8v p = *(const ushort8v*)(lds + l15 * 136 + kt_loc * 32 + l4 * 8);
    const int g = nt * 32 + kb * 4 + kt_loc;
    __builtin_nontemporal_store(p, (ushort8v*)(Wallp + ((size_t)g * 64 + l) * 8));
  } else {
    for (int n = t; n < 320; n += 256) {
      float v = 0.f;
      if (n < 32)       v = bnum [n];
      else if (n < 230) v = bcat [n - 32];
      else if (n < 238) v = bbin [n - 230];
      else if (n < 240) v = blike[n - 238];
      else if (n < 294) v = bmask[n - 240];
      __builtin_nontemporal_store(v, ball + n);
    }
  }
}

// ---------------- two-phase fused decoder core (r13 structure + gn precompute) ----------------
template<int G>
__device__ __forceinline__ void run_phases(
    const int w, const int lane, const int l15, const int l4, const int nt0,
    const int tid, const int r0,
    const unsigned short* __restrict__ W1p, const unsigned short* __restrict__ Wallp,
    const float* __restrict__ b1,
    unsigned char* smem, f32x4 (&acc)[4][3], float (&gn)[8]) {

  constexpr int RING = (G == 3) ? 6 : 8;   // wq2 VGPR: G=3: 72, G=2: 64

  unsigned short* zs = (unsigned short*)smem;          // [64][136] bf16
  unsigned char* hbase  = smem + 17408;                // 8 x 16 KB h tiles
  unsigned char* mytile = hbase + w * 16384;

  f32x4 hb1[8];
  #pragma unroll
  for (int ct = 0; ct < 8; ++ct)
    hb1[ct] = *(const f32x4*)(b1 + w * 128 + ct * 16 + l4 * 4);

  bf16x8 za[4][4];
  #pragma unroll
  for (int rt = 0; rt < 4; ++rt)
    #pragma unroll
    for (int ks = 0; ks < 4; ++ks)
      za[rt][ks] = *(const bf16x8*)(zs + (rt * 16 + l15) * 136 + ks * 32 + l4 * 8);

  bf16x8 wq1[2][4];
  const unsigned short* w1b = W1p + (size_t)w * 16384 + lane * 8;
  #pragma unroll
  for (int ct = 0; ct < 2; ++ct) {
    const unsigned short* p = w1b + ct * 2048;
    gl16o<0>(wq1[ct][0], p); gl16o<1024>(wq1[ct][1], p);
    gl16o<2048>(wq1[ct][2], p); gl16o<3072>(wq1[ct][3], p);
  }

  bf16x8 wq2[RING][G];
  const unsigned short* w2b = Wallp + lane * 8;

  // ---- gumbel-noise precompute (pure index math, no GEMM data) ----
  // Placed between the wq1 issue and phase 1's first waitv: the waitv's
  // sched_barrier(0) is a full scheduling fence, so this provably executes
  // HERE — filling the cold weight-load latency bubble and emptying the
  // formerly-serial epilogue tail (~240 VALU ops/thread).
  {
    int c = 230 + (tid >> 3);
    unsigned ka, kb; int Nh, head;
    if (c < 238)      { ka = NK0.a; kb = NK0.b; Nh = 8;  head = c - 230; }
    else if (c < 240) { ka = NK1.a; kb = NK1.b; Nh = 2;  head = c - 238; }
    else              { ka = NK2.a; kb = NK2.b; Nh = 54; head = c - 240; }
    #pragma unroll
    for (int q = 0; q < 2; ++q)
      #pragma unroll
      for (int e = 0; e < 4; ++e) {
        int rl = (tid & 7) * 4 + q * 32 + e;
        unsigned jj = (unsigned)((r0 + rl) * Nh + head);
        TF2 t = threefry2x32(ka, kb, 0u, jj);
        unsigned bits = t.a ^ t.b;
        float u = __uint_as_float((bits >> 9) | 0x3f800000u) - 1.0f;
        gn[q * 4 + e] = -__logf(-__logf(u + 1e-20f) + 1e-20f);
      }
  }

  // ---- phase 1 ----
  #pragma unroll
  for (int ct = 0; ct < 8; ++ct) {
    if (ct < 7) waitv<4>();
    else        waitv<G * RING>();   // wq1 g7 arrived; all RING wq2 groups in flight
    f32x4 a[4] = {};
    #pragma unroll
    for (int ks = 0; ks < 4; ++ks)
      #pragma unroll
      for (int rt = 0; rt < 4; ++rt)
        a[rt] = __builtin_amdgcn_mfma_f32_16x16x32_bf16(wq1[ct & 1][ks], za[rt][ks], a[rt], 0, 0, 0);
    #pragma unroll
    for (int rt = 0; rt < 4; ++rt) {
      float v0 = fmaxf(a[rt][0] + hb1[ct][0], 0.f);
      float v1 = fmaxf(a[rt][1] + hb1[ct][1], 0.f);
      float v2 = fmaxf(a[rt][2] + hb1[ct][2], 0.f);
      float v3 = fmaxf(a[rt][3] + hb1[ct][3], 0.f);
      uint2v u;
      u[0] = (unsigned)f2bf(v0) | ((unsigned)f2bf(v1) << 16);
      u[1] = (unsigned)f2bf(v2) | ((unsigned)f2bf(v3) << 16);
      const int byte = ((ct >> 1) * 4 + rt) * 1024
                     + ((ct & 1) * 2 + (l4 >> 1)) * 256
                     + l15 * 16 + (l4 & 1) * 8;
      *(uint2v*)(mytile + byte) = u;
    }
    if (ct < 6) {
      const unsigned short* p = w1b + (ct + 2) * 2048;
      gl16o<0>(wq1[ct & 1][0], p); gl16o<1024>(wq1[ct & 1][1], p);
      gl16o<2048>(wq1[ct & 1][2], p); gl16o<3072>(wq1[ct & 1][3], p);
    } else if (ct == 6) {
      #pragma unroll
      for (int g = 0; g < RING; ++g)
        #pragma unroll
        for (int cc = 0; cc < G; ++cc)
          gl16(wq2[g][cc], w2b + (size_t)((nt0 + cc) * 32 + g) * 512);
    }
  }

  LGKM_BARRIER();    // h visible to all waves; weight prefetches stay in flight

  // ---- phase 2 ----
  #pragma unroll
  for (int rt = 0; rt < 4; ++rt)
    #pragma unroll
    for (int ct = 0; ct < 3; ++ct)
      acc[rt][ct] = (f32x4){0.f, 0.f, 0.f, 0.f};

  #pragma unroll
  for (int g = 0; g < 32; ++g) {
    const int rem = 31 - g;          // constant after unroll
    if (rem >= RING - 1)  waitv<G * (RING - 1)>();
    else if (rem == 6)    waitv<G * 6>();
    else if (rem == 5)    waitv<G * 5>();
    else if (rem == 4)    waitv<G * 4>();
    else if (rem == 3)    waitv<G * 3>();
    else if (rem == 2)    waitv<G * 2>();
    else if (rem == 1)    waitv<G * 1>();
    else                  waitv<0>();
    const unsigned char* hc = hbase + (g >> 2) * 16384 + (g & 3) * 4096 + lane * 16;
    #pragma unroll
    for (int rt = 0; rt < 4; ++rt) {
      bf16x8 ha = *(const bf16x8*)(hc + rt * 1024);
      #pragma unroll
      for (int ct = 0; ct < G; ++ct)
        acc[rt][ct] = __builtin_amdgcn_mfma_f32_16x16x32_bf16(ha, wq2[g % RING][ct], acc[rt][ct], 0, 0, 0);
    }
    if (g + RING < 32) {
      #pragma unroll
      for (int cc = 0; cc < G; ++cc)
        gl16(wq2[g % RING][cc], w2b + (size_t)((nt0 + cc) * 32 + (g + RING)) * 512);
    }
  }
}

// ---------------- main kernel: 256 WGs x 512 thr (8 waves), 64 rows/WG ----------------
__global__ __launch_bounds__(512, 2) void decoder_kernel(
    const float* __restrict__ z, const float* __restrict__ b1,
    const unsigned short* __restrict__ W1p, const unsigned short* __restrict__ Wallp,
    const float* __restrict__ ball, float* __restrict__ out) {
  __shared__ __align__(16) unsigned char smem[148480];
  unsigned short* zs = (unsigned short*)smem;
  float* outs = (float*)smem;

  const int tid  = threadIdx.x;
  const int lane = tid & 63;
  const int w    = tid >> 6;
  const int l15  = lane & 15;
  const int l4   = lane >> 4;
  const int r0   = blockIdx.x * 64;

  // ---- stage z tile -> LDS bf16 (cached loads — z L2-resident across replays) ----
  #pragma unroll
  for (int it = 0; it < 2; ++it) {
    int ch  = tid + it * 512;
    int row = ch >> 4;
    int k0  = (ch & 15) * 8;
    const float* src = z + (size_t)(r0 + row) * LATD + k0;
    f32x4 f0 = *(const f32x4*)src;
    f32x4 f1 = *(const f32x4*)(src + 4);
    ushort8v p;
    p[0] = f2bf(f0[0]); p[1] = f2bf(f0[1]); p[2] = f2bf(f0[2]); p[3] = f2bf(f0[3]);
    p[4] = f2bf(f1[0]); p[5] = f2bf(f1[1]); p[6] = f2bf(f1[2]); p[7] = f2bf(f1[3]);
    *(ushort8v*)(zs + row * 136 + k0) = p;
  }
  __syncthreads();   // full drain OK: no asm loads issued yet

  const int cb  = (w < 4) ? w * 48 : 192 + (w - 4) * 32;
  const int nt0 = (w < 4) ? w * 3  : 12 + (w - 4) * 2;
  const int myG = (w < 4) ? 3 : 2;

  f32x4 acc[4][3];
  float gn[8];
  if (w < 4) run_phases<3>(w, lane, l15, l4, nt0, tid, r0, W1p, Wallp, b1, smem, acc, gn);
  else       run_phases<2>(w, lane, l15, l4, nt0, tid, r0, W1p, Wallp, b1, smem, acc, gn);

  __syncthreads();   // all h reads done; LDS becomes outs

  #pragma unroll
  for (int ct = 0; ct < 3; ++ct) {
    if (ct < myG) {
      float b2 = ball[cb + ct * 16 + l15];
      #pragma unroll
      for (int rt = 0; rt < 4; ++rt)
        #pragma unroll
        for (int j = 0; j < 4; ++j)
          outs[(rt * 16 + l4 * 4 + j) * 321 + cb + ct * 16 + l15] = acc[rt][ct][j] + b2;
    }
  }
  __syncthreads();

  // ---- write num + cat blocks (contiguous float4, NT) ----
  {
    constexpr int cards[13] = {32,10,20,15,8,30,12,5,25,6,40,18,9};
    constexpr int cbase[13] = {0,32,42,62,77,85,115,127,132,157,163,203,221};
    #pragma unroll
    for (int blk = 0; blk < 13; ++blk) {
      const int card = cards[blk];
      const int cbs  = cbase[blk];
      float* gout = out + (size_t)B_ROWS * cbs + (size_t)r0 * card;
      for (int v = tid; v < card * 16; v += 512) {
        int gg = v * 4;
        f32x4v vbuf;
        #pragma unroll
        for (int e = 0; e < 4; ++e) {
          int ge = gg + e;
          int brow = ge / card;
          int j = ge - brow * card;
          vbuf[e] = outs[brow * 321 + cbs + j];
        }
        __builtin_nontemporal_store(vbuf, (f32x4v*)(gout + gg));
      }
    }
  }

  // ---- gumbel-sigmoid heads: just sigmoid(x + precomputed gn) ----
  {
    int c = 230 + (tid >> 3);
    #pragma unroll
    for (int q = 0; q < 2; ++q) {
      int rq = (tid & 7) * 4 + q * 32;
      f32x4v vbuf;
      #pragma unroll
      for (int e = 0; e < 4; ++e) {
        float x = outs[(rq + e) * 321 + c];
        vbuf[e] = 1.0f / (1.0f + __expf(-(x + gn[q * 4 + e])));
      }
      __builtin_nontemporal_store(vbuf, (f32x4v*)(out + (size_t)B_ROWS * c + r0 + rq));
    }
  }
}

// ---------------- launch ----------------
extern "C" void kernel_launch(void* const* d_in, const int* in_sizes, int n_in,
                              void* d_out, int out_size, void* d_ws, size_t ws_size,
                              hipStream_t stream) {
  const float* z     = (const float*)d_in[0];
  const float* W1    = (const float*)d_in[1];
  const float* b1    = (const float*)d_in[2];
  const float* Wnum  = (const float*)d_in[3];
  const float* bnum  = (const float*)d_in[4];
  const float* Wcat  = (const float*)d_in[5];
  const float* bcat  = (const float*)d_in[6];
  const float* Wbin  = (const float*)d_in[7];
  const float* bbin  = (const float*)d_in[8];
  const float* Wlike = (const float*)d_in[9];
  const float* blike = (const float*)d_in[10];
  const float* Wmask = (const float*)d_in[11];
  const float* bmask = (const float*)d_in[12];

  unsigned short* W1p   = (unsigned short*)d_ws;            // 131072 bf16 = 256 KB
  unsigned short* Wallp = W1p + 131072;                     // 327680 bf16 = 640 KB
  float*          ball  = (float*)(Wallp + 327680);         // 320 f32

  prep_kernel<<<225, 256, 0, stream>>>(
      W1, Wnum, Wcat, Wbin, Wlike, Wmask, bnum, bcat, bbin, blike, bmask,
      W1p, Wallp, ball);

  decoder_kernel<<<B_ROWS / 64, 512, 0, stream>>>(
      z, b1, W1p, Wallp, ball, (float*)d_out);
}

// Round 18
// 28.286 us; speedup vs baseline: 1.0804x; 1.0077x over previous
//
#include <hip/hip_runtime.h>
#include <stdint.h>

// ---------------- problem constants ----------------
#define B_ROWS 16384
#define LATD   128
#define HIDD   1024

typedef __bf16 bf16x8 __attribute__((ext_vector_type(8)));
typedef float  f32x4  __attribute__((ext_vector_type(4)));
typedef float  f32x4v __attribute__((ext_vector_type(4)));
typedef unsigned short ushort8v __attribute__((ext_vector_type(8)));
typedef unsigned int   uint2v   __attribute__((ext_vector_type(2)));

// ---------------- asm helpers: unsinkable weight loads + counted waits ----------------
template<int N> __device__ __forceinline__ void waitv() {
  asm volatile("s_waitcnt vmcnt(%0)" :: "i"(N) : "memory");
  __builtin_amdgcn_sched_barrier(0);   // rule-18: no MFMA may hoist above the wait
}
__device__ __forceinline__ void gl16(bf16x8& r, const unsigned short* p) {
  asm volatile("global_load_dwordx4 %0, %1, off" : "=v"(r) : "v"(p));
}
template<int OFF> __device__ __forceinline__ void gl16o(bf16x8& r, const unsigned short* p) {
  asm volatile("global_load_dwordx4 %0, %1, off offset:%2" : "=v"(r) : "v"(p), "i"(OFF));
}
// barrier that drains LDS ops only — asm weight loads stay in flight
#define LGKM_BARRIER() do {                                        \
    asm volatile("s_waitcnt lgkmcnt(0)" ::: "memory");             \
    __builtin_amdgcn_s_barrier();                                  \
    asm volatile("" ::: "memory");                                 \
  } while (0)

// ---------------- threefry2x32 (matches JAX, partitionable default) ----------------
struct TF2 { unsigned int a, b; };

#define TF_R(x0,x1,r) { x0 += x1; x1 = ((x1 << (r)) | (x1 >> (32 - (r)))); x1 ^= x0; }

__host__ __device__ constexpr TF2 threefry2x32(unsigned k0, unsigned k1, unsigned c0, unsigned c1) {
  unsigned ks2 = k0 ^ k1 ^ 0x1BD11BDAu;
  unsigned x0 = c0 + k0, x1 = c1 + k1;
  TF_R(x0,x1,13) TF_R(x0,x1,15) TF_R(x0,x1,26) TF_R(x0,x1,6)
  x0 += k1;  x1 += ks2 + 1u;
  TF_R(x0,x1,17) TF_R(x0,x1,29) TF_R(x0,x1,16) TF_R(x0,x1,24)
  x0 += ks2; x1 += k0 + 2u;
  TF_R(x0,x1,13) TF_R(x0,x1,15) TF_R(x0,x1,26) TF_R(x0,x1,6)
  x0 += k0;  x1 += k1 + 3u;
  TF_R(x0,x1,17) TF_R(x0,x1,29) TF_R(x0,x1,16) TF_R(x0,x1,24)
  x0 += k1;  x1 += ks2 + 4u;
  TF_R(x0,x1,13) TF_R(x0,x1,15) TF_R(x0,x1,26) TF_R(x0,x1,6)
  x0 += ks2; x1 += k0 + 5u;
  return {x0, x1};
}

constexpr TF2 NK0 = threefry2x32(0u, 1u, 0u, 0u);  // bin heads
constexpr TF2 NK1 = threefry2x32(0u, 1u, 0u, 1u);  // like heads
constexpr TF2 NK2 = threefry2x32(0u, 1u, 0u, 2u);  // mask heads

__device__ __forceinline__ unsigned short f2bf(float f) {
  unsigned u = __float_as_uint(f);
  return (unsigned short)((u + 0x7fffu + ((u >> 16) & 1u)) >> 16);
}

// ---------------- prep v4 (r15, kept) ----------------
__global__ __launch_bounds__(256) void prep_kernel(
    const float* __restrict__ W1,
    const float* __restrict__ Wnum, const float* __restrict__ Wcat,
    const float* __restrict__ Wbin, const float* __restrict__ Wlike,
    const float* __restrict__ Wmask,
    const float* __restrict__ bnum, const float* __restrict__ bcat,
    const float* __restrict__ bbin, const float* __restrict__ blike,
    const float* __restrict__ bmask,
    unsigned short* __restrict__ W1p,
    unsigned short* __restrict__ Wallp,
    float* __restrict__ ball) {
  __shared__ __align__(16) unsigned short lds[16 * 136];
  const int b = blockIdx.x, t = threadIdx.x;

  if (b < 64) {
    const int n0 = b * 16;
    const int nq = t & 15;
    float v[8];
    #pragma unroll
    for (int i = 0; i < 8; ++i) {
      int k = i * 16 + (t >> 4);
      v[i] = W1[(size_t)k * HIDD + n0 + nq];
    }
    #pragma unroll
    for (int i = 0; i < 8; ++i) {
      int k = i * 16 + (t >> 4);
      lds[nq * 136 + k] = f2bf(v[i]);
    }
    __syncthreads();
    const int ks = t >> 6, l = t & 63;
    const int l15 = l & 15, l4 = (l >> 4);
    ushort8v p = *(const ushort8v*)(lds + l15 * 136 + ks * 32 + l4 * 8);
    __builtin_nontemporal_store(p, (ushort8v*)(W1p + ((size_t)(b * 4 + ks) * 64 + l) * 8));
  } else if (b < 224) {
    const int q  = b - 64;
    const int nt = q >> 3, kb = q & 7;
    const int n0 = nt * 16, k0 = kb * 128;
    const int n = n0 + (t & 15);
    const float* src = nullptr; int stride = 0;
    if (n < 32)       { src = Wnum  + n;         stride = 32;  }
    else if (n < 230) { src = Wcat  + (n - 32);  stride = 198; }
    else if (n < 238) { src = Wbin  + (n - 230); stride = 8;   }
    else if (n < 240) { src = Wlike + (n - 238); stride = 2;   }
    else if (n < 294) { src = Wmask + (n - 240); stride = 54;  }
    float v[8];
    if (src) {
      #pragma unroll
      for (int i = 0; i < 8; ++i) {
        int kk_loc = i * 16 + (t >> 4);
        v[i] = src[(size_t)(k0 + kk_loc) * stride];
      }
    } else {
      #pragma unroll
      for (int i = 0; i < 8; ++i) v[i] = 0.f;
    }
    #pragma unroll
    for (int i = 0; i < 8; ++i) {
      int kk_loc = i * 16 + (t >> 4);
      lds[(t & 15) * 136 + kk_loc] = f2bf(v[i]);
    }
    __syncthreads();
    const int kt_loc = t >> 6, l = t & 63;
    const int l15 = l & 15, l4 = (l >> 4);
    ushort8v p = *(const ushort8v*)(lds + l15 * 136 + kt_loc * 32 + l4 * 8);
    const int g = nt * 32 + kb * 4 + kt_loc;
    __builtin_nontemporal_store(p, (ushort8v*)(Wallp + ((size_t)g * 64 + l) * 8));
  } else {
    for (int n = t; n < 320; n += 256) {
      float v = 0.f;
      if (n < 32)       v = bnum [n];
      else if (n < 230) v = bcat [n - 32];
      else if (n < 238) v = bbin [n - 230];
      else if (n < 240) v = blike[n - 238];
      else if (n < 294) v = bmask[n - 240];
      __builtin_nontemporal_store(v, ball + n);
    }
  }
}

// ---------------- two-phase fused decoder core (r17 + phase-2 ds_read dbuf) ----------------
template<int G>
__device__ __forceinline__ void run_phases(
    const int w, const int lane, const int l15, const int l4, const int nt0,
    const int tid, const int r0,
    const unsigned short* __restrict__ W1p, const unsigned short* __restrict__ Wallp,
    const float* __restrict__ b1,
    unsigned char* smem, f32x4 (&acc)[4][3], float (&gn)[8]) {

  constexpr int RING = (G == 3) ? 6 : 8;   // wq2 VGPR: G=3: 72, G=2: 64

  unsigned short* zs = (unsigned short*)smem;          // [64][136] bf16
  unsigned char* hbase  = smem + 17408;                // 8 x 16 KB h tiles
  unsigned char* mytile = hbase + w * 16384;

  f32x4 hb1[8];
  #pragma unroll
  for (int ct = 0; ct < 8; ++ct)
    hb1[ct] = *(const f32x4*)(b1 + w * 128 + ct * 16 + l4 * 4);

  bf16x8 za[4][4];
  #pragma unroll
  for (int rt = 0; rt < 4; ++rt)
    #pragma unroll
    for (int ks = 0; ks < 4; ++ks)
      za[rt][ks] = *(const bf16x8*)(zs + (rt * 16 + l15) * 136 + ks * 32 + l4 * 8);

  bf16x8 wq1[2][4];
  const unsigned short* w1b = W1p + (size_t)w * 16384 + lane * 8;
  #pragma unroll
  for (int ct = 0; ct < 2; ++ct) {
    const unsigned short* p = w1b + ct * 2048;
    gl16o<0>(wq1[ct][0], p); gl16o<1024>(wq1[ct][1], p);
    gl16o<2048>(wq1[ct][2], p); gl16o<3072>(wq1[ct][3], p);
  }

  bf16x8 wq2[RING][G];
  const unsigned short* w2b = Wallp + lane * 8;

  // ---- gumbel-noise precompute (fills the cold weight-load bubble; r17) ----
  {
    int c = 230 + (tid >> 3);
    unsigned ka, kb; int Nh, head;
    if (c < 238)      { ka = NK0.a; kb = NK0.b; Nh = 8;  head = c - 230; }
    else if (c < 240) { ka = NK1.a; kb = NK1.b; Nh = 2;  head = c - 238; }
    else              { ka = NK2.a; kb = NK2.b; Nh = 54; head = c - 240; }
    #pragma unroll
    for (int q = 0; q < 2; ++q)
      #pragma unroll
      for (int e = 0; e < 4; ++e) {
        int rl = (tid & 7) * 4 + q * 32 + e;
        unsigned jj = (unsigned)((r0 + rl) * Nh + head);
        TF2 t = threefry2x32(ka, kb, 0u, jj);
        unsigned bits = t.a ^ t.b;
        float u = __uint_as_float((bits >> 9) | 0x3f800000u) - 1.0f;
        gn[q * 4 + e] = -__logf(-__logf(u + 1e-20f) + 1e-20f);
      }
  }

  // ---- phase 1 ----
  #pragma unroll
  for (int ct = 0; ct < 8; ++ct) {
    if (ct < 7) waitv<4>();
    else        waitv<G * RING>();   // wq1 g7 arrived; all RING wq2 groups in flight
    f32x4 a[4] = {};
    #pragma unroll
    for (int ks = 0; ks < 4; ++ks)
      #pragma unroll
      for (int rt = 0; rt < 4; ++rt)
        a[rt] = __builtin_amdgcn_mfma_f32_16x16x32_bf16(wq1[ct & 1][ks], za[rt][ks], a[rt], 0, 0, 0);
    #pragma unroll
    for (int rt = 0; rt < 4; ++rt) {
      float v0 = fmaxf(a[rt][0] + hb1[ct][0], 0.f);
      float v1 = fmaxf(a[rt][1] + hb1[ct][1], 0.f);
      float v2 = fmaxf(a[rt][2] + hb1[ct][2], 0.f);
      float v3 = fmaxf(a[rt][3] + hb1[ct][3], 0.f);
      uint2v u;
      u[0] = (unsigned)f2bf(v0) | ((unsigned)f2bf(v1) << 16);
      u[1] = (unsigned)f2bf(v2) | ((unsigned)f2bf(v3) << 16);
      const int byte = ((ct >> 1) * 4 + rt) * 1024
                     + ((ct & 1) * 2 + (l4 >> 1)) * 256
                     + l15 * 16 + (l4 & 1) * 8;
      *(uint2v*)(mytile + byte) = u;
    }
    if (ct < 6) {
      const unsigned short* p = w1b + (ct + 2) * 2048;
      gl16o<0>(wq1[ct & 1][0], p); gl16o<1024>(wq1[ct & 1][1], p);
      gl16o<2048>(wq1[ct & 1][2], p); gl16o<3072>(wq1[ct & 1][3], p);
    } else if (ct == 6) {
      #pragma unroll
      for (int g = 0; g < RING; ++g)
        #pragma unroll
        for (int cc = 0; cc < G; ++cc)
          gl16(wq2[g][cc], w2b + (size_t)((nt0 + cc) * 32 + g) * 512);
    }
  }

  LGKM_BARRIER();    // h visible to all waves; weight prefetches stay in flight

  // ---- phase 2 (NEW: h ds_reads double-buffered — iteration g issues g+1's reads
  //      right after the vmcnt fence, so their ~120-cyc LDS latency hides under the
  //      MFMAs + the next weight wait instead of serializing with it) ----
  #pragma unroll
  for (int rt = 0; rt < 4; ++rt)
    #pragma unroll
    for (int ct = 0; ct < 3; ++ct)
      acc[rt][ct] = (f32x4){0.f, 0.f, 0.f, 0.f};

  bf16x8 ha[2][4];
  {
    const unsigned char* hc0 = hbase + lane * 16;      // g=0 tile
    #pragma unroll
    for (int rt = 0; rt < 4; ++rt)
      ha[0][rt] = *(const bf16x8*)(hc0 + rt * 1024);
  }

  #pragma unroll
  for (int g = 0; g < 32; ++g) {
    const int rem = 31 - g;          // constant after unroll
    if (rem >= RING - 1)  waitv<G * (RING - 1)>();
    else if (rem == 6)    waitv<G * 6>();
    else if (rem == 5)    waitv<G * 5>();
    else if (rem == 4)    waitv<G * 4>();
    else if (rem == 3)    waitv<G * 3>();
    else if (rem == 2)    waitv<G * 2>();
    else if (rem == 1)    waitv<G * 1>();
    else                  waitv<0>();
    // issue NEXT iteration's h reads first (fly under this iteration's MFMAs)
    if (g + 1 < 32) {
      const unsigned char* hcn = hbase + ((g + 1) >> 2) * 16384 + ((g + 1) & 3) * 4096 + lane * 16;
      #pragma unroll
      for (int rt = 0; rt < 4; ++rt)
        ha[(g + 1) & 1][rt] = *(const bf16x8*)(hcn + rt * 1024);
    }
    #pragma unroll
    for (int rt = 0; rt < 4; ++rt)
      #pragma unroll
      for (int ct = 0; ct < G; ++ct)
        acc[rt][ct] = __builtin_amdgcn_mfma_f32_16x16x32_bf16(ha[g & 1][rt], wq2[g % RING][ct], acc[rt][ct], 0, 0, 0);
    if (g + RING < 32) {
      #pragma unroll
      for (int cc = 0; cc < G; ++cc)
        gl16(wq2[g % RING][cc], w2b + (size_t)((nt0 + cc) * 32 + (g + RING)) * 512);
    }
  }
}

// ---------------- main kernel: 256 WGs x 512 thr (8 waves), 64 rows/WG ----------------
__global__ __launch_bounds__(512, 2) void decoder_kernel(
    const float* __restrict__ z, const float* __restrict__ b1,
    const unsigned short* __restrict__ W1p, const unsigned short* __restrict__ Wallp,
    const float* __restrict__ ball, float* __restrict__ out) {
  __shared__ __align__(16) unsigned char smem[148480];
  unsigned short* zs = (unsigned short*)smem;
  float* outs = (float*)smem;

  const int tid  = threadIdx.x;
  const int lane = tid & 63;
  const int w    = tid >> 6;
  const int l15  = lane & 15;
  const int l4   = lane >> 4;
  const int r0   = blockIdx.x * 64;

  // ---- stage z tile -> LDS bf16 (cached loads — z L2-resident across replays) ----
  #pragma unroll
  for (int it = 0; it < 2; ++it) {
    int ch  = tid + it * 512;
    int row = ch >> 4;
    int k0  = (ch & 15) * 8;
    const float* src = z + (size_t)(r0 + row) * LATD + k0;
    f32x4 f0 = *(const f32x4*)src;
    f32x4 f1 = *(const f32x4*)(src + 4);
    ushort8v p;
    p[0] = f2bf(f0[0]); p[1] = f2bf(f0[1]); p[2] = f2bf(f0[2]); p[3] = f2bf(f0[3]);
    p[4] = f2bf(f1[0]); p[5] = f2bf(f1[1]); p[6] = f2bf(f1[2]); p[7] = f2bf(f1[3]);
    *(ushort8v*)(zs + row * 136 + k0) = p;
  }
  __syncthreads();   // full drain OK: no asm loads issued yet

  const int cb  = (w < 4) ? w * 48 : 192 + (w - 4) * 32;
  const int nt0 = (w < 4) ? w * 3  : 12 + (w - 4) * 2;
  const int myG = (w < 4) ? 3 : 2;

  f32x4 acc[4][3];
  float gn[8];
  if (w < 4) run_phases<3>(w, lane, l15, l4, nt0, tid, r0, W1p, Wallp, b1, smem, acc, gn);
  else       run_phases<2>(w, lane, l15, l4, nt0, tid, r0, W1p, Wallp, b1, smem, acc, gn);

  __syncthreads();   // all h reads done; LDS becomes outs

  #pragma unroll
  for (int ct = 0; ct < 3; ++ct) {
    if (ct < myG) {
      float b2 = ball[cb + ct * 16 + l15];
      #pragma unroll
      for (int rt = 0; rt < 4; ++rt)
        #pragma unroll
        for (int j = 0; j < 4; ++j)
          outs[(rt * 16 + l4 * 4 + j) * 321 + cb + ct * 16 + l15] = acc[rt][ct][j] + b2;
    }
  }
  __syncthreads();

  // ---- write num + cat blocks (contiguous float4, NT) ----
  {
    constexpr int cards[13] = {32,10,20,15,8,30,12,5,25,6,40,18,9};
    constexpr int cbase[13] = {0,32,42,62,77,85,115,127,132,157,163,203,221};
    #pragma unroll
    for (int blk = 0; blk < 13; ++blk) {
      const int card = cards[blk];
      const int cbs  = cbase[blk];
      float* gout = out + (size_t)B_ROWS * cbs + (size_t)r0 * card;
      for (int v = tid; v < card * 16; v += 512) {
        int gg = v * 4;
        f32x4v vbuf;
        #pragma unroll
        for (int e = 0; e < 4; ++e) {
          int ge = gg + e;
          int brow = ge / card;
          int j = ge - brow * card;
          vbuf[e] = outs[brow * 321 + cbs + j];
        }
        __builtin_nontemporal_store(vbuf, (f32x4v*)(gout + gg));
      }
    }
  }

  // ---- gumbel-sigmoid heads: just sigmoid(x + precomputed gn) ----
  {
    int c = 230 + (tid >> 3);
    #pragma unroll
    for (int q = 0; q < 2; ++q) {
      int rq = (tid & 7) * 4 + q * 32;
      f32x4v vbuf;
      #pragma unroll
      for (int e = 0; e < 4; ++e) {
        float x = outs[(rq + e) * 321 + c];
        vbuf[e] = 1.0f / (1.0f + __expf(-(x + gn[q * 4 + e])));
      }
      __builtin_nontemporal_store(vbuf, (f32x4v*)(out + (size_t)B_ROWS * c + r0 + rq));
    }
  }
}

// ---------------- launch ----------------
extern "C" void kernel_launch(void* const* d_in, const int* in_sizes, int n_in,
                              void* d_out, int out_size, void* d_ws, size_t ws_size,
                              hipStream_t stream) {
  const float* z     = (const float*)d_in[0];
  const float* W1    = (const float*)d_in[1];
  const float* b1    = (const float*)d_in[2];
  const float* Wnum  = (const float*)d_in[3];
  const float* bnum  = (const float*)d_in[4];
  const float* Wcat  = (const float*)d_in[5];
  const float* bcat  = (const float*)d_in[6];
  const float* Wbin  = (const float*)d_in[7];
  const float* bbin  = (const float*)d_in[8];
  const float* Wlike = (const float*)d_in[9];
  const float* blike = (const float*)d_in[10];
  const float* Wmask = (const float*)d_in[11];
  const float* bmask = (const float*)d_in[12];

  unsigned short* W1p   = (unsigned short*)d_ws;            // 131072 bf16 = 256 KB
  unsigned short* Wallp = W1p + 131072;                     // 327680 bf16 = 640 KB
  float*          ball  = (float*)(Wallp + 327680);         // 320 f32

  prep_kernel<<<225, 256, 0, stream>>>(
      W1, Wnum, Wcat, Wbin, Wlike, Wmask, bnum, bcat, bbin, blike, bmask,
      W1p, Wallp, ball);

  decoder_kernel<<<B_ROWS / 64, 512, 0, stream>>>(
      z, b1, W1p, Wallp, ball, (float*)d_out);
}